// Round 14
// baseline (386.534 us; speedup 1.0000x reference)
//
#include <hip/hip_runtime.h>

// Problem constants (fixed by reference): B=128, L=256, F=P=4, IN=1024, H=256, C=7
#define NN 32768        // N = B*L
#define INF 1024
#define HF 256

typedef __bf16 bf16x8 __attribute__((ext_vector_type(8)));
typedef float f32x4 __attribute__((ext_vector_type(4)));
typedef unsigned short u16x8 __attribute__((ext_vector_type(8)));

__device__ __forceinline__ float bf2f(unsigned short u) {
  union { unsigned int i; float f; } v; v.i = ((unsigned int)u) << 16; return v.f;
}
__device__ __forceinline__ unsigned short f2bf(float f) {
  union { float f; unsigned int i; } v; v.f = f;
  unsigned int x = v.i;
  return (unsigned short)((x + 0x7fffu + ((x >> 16) & 1u)) >> 16);  // RNE
}

// async global->LDS, 16B per lane; SOURCE is per-lane, DEST = uniform base + lane*16
__device__ __forceinline__ void ld_lds16(const unsigned short* g, unsigned short* l) {
  __builtin_amdgcn_global_load_lds(
      (__attribute__((address_space(1))) const unsigned int*)g,
      (__attribute__((address_space(3))) unsigned int*)l, 16, 0, 0);
}

// pack 8 fp32 -> 8 bf16 (as u16x8 bit pattern) via v_cvt_pk_bf16_f32 (RNE = f2bf)
__device__ __forceinline__ u16x8 cvt8u(f32x4 lo, f32x4 hi) {
  union { unsigned int u[4]; u16x8 v; } r;
  asm("v_cvt_pk_bf16_f32 %0, %1, %2" : "=v"(r.u[0]) : "v"(lo[0]), "v"(lo[1]));
  asm("v_cvt_pk_bf16_f32 %0, %1, %2" : "=v"(r.u[1]) : "v"(lo[2]), "v"(lo[3]));
  asm("v_cvt_pk_bf16_f32 %0, %1, %2" : "=v"(r.u[2]) : "v"(hi[0]), "v"(hi[1]));
  asm("v_cvt_pk_bf16_f32 %0, %1, %2" : "=v"(r.u[3]) : "v"(hi[2]), "v"(hi[3]));
  return r.v;
}

// ---- prep (weights only): 288 blocks, 64x64 LDS transpose (coalesced both sides)
// WbigT[n][k] (1024x1024) = [W0|W1|Wroot|Wskip]^T ; WsmT[n][k] (256x512) = [Wgrt;Wrel]^T
__global__ __launch_bounds__(256)
void diagcn_prep(const float* __restrict__ Wrgcn, const float* __restrict__ Wroot,
                 const float* __restrict__ Wskip, const float* __restrict__ Wgrt,
                 const float* __restrict__ Wrel, unsigned short* __restrict__ WbigT,
                 unsigned short* __restrict__ WsmT, float* __restrict__ loss) {
  int tb = blockIdx.x;
  if (tb == 0 && threadIdx.x == 0) loss[0] = 0.f;
  __shared__ float tile[64 * 65];
  const float* src;
  int k0, ncol0;
  unsigned short* dst;
  int ldd, nrow0;
  if (tb < 256) {            // WbigT tiles: tn 0..15, tk 0..15
    int tn = tb >> 4, tk = tb & 15;
    int mat = tn >> 2;
    src = (mat == 0) ? Wrgcn : (mat == 1) ? (Wrgcn + 262144) : (mat == 2) ? Wroot : Wskip;
    k0 = tk * 64; ncol0 = (tn & 3) * 64;
    dst = WbigT; ldd = 1024; nrow0 = tn * 64;
  } else {                   // WsmT tiles: tn 0..3, tk 0..7
    int t2 = tb - 256;
    int tn = t2 >> 3, tk = t2 & 7;
    src = (tk < 4) ? Wgrt : Wrel;
    k0 = (tk & 3) * 64; ncol0 = tn * 64;
    dst = WsmT; ldd = 512; nrow0 = tn * 64;
  }
  int kdst0 = (tb < 256) ? k0 : (((tb - 256) & 7) * 64);
  int c = threadIdx.x & 63, rb = threadIdx.x >> 6;
#pragma unroll
  for (int it = 0; it < 16; ++it) {
    int r = rb + it * 4;
    tile[r * 65 + c] = src[(size_t)(k0 + r) * 256 + ncol0 + c];
  }
  __syncthreads();
  int kk = threadIdx.x & 63;
#pragma unroll
  for (int it = 0; it < 16; ++it) {
    int nn = rb + it * 4;
    dst[(size_t)(nrow0 + nn) * ldd + kdst0 + kk] = f2bf(tile[kk * 65 + nn]);
  }
}

// ---- GEMM1 v8: Y[32768 x 1024] = bf16(X) @ WbigT^T, fp32 X converted in-staging.
// 128x256 tile, 512 threads (8 waves 2m x 4n -> 64x64/wave, acc = 64 VGPR), BK=32.
// OCCUPANCY lever (every prior variant was 1 block/CU, Occupancy ~21%):
//   LDS = 3 bufs x (A-bf16 [128][32] 8KB + B-bf16 [256][32] 16KB) = 72 KB
//   + __launch_bounds__(512,4) -> 2 blocks/CU (144KB LDS, 4 waves/SIMD).
// A path: reg-stage fp32 (2 x 16B loads/thread, issued one tile early) -> cvt_pk
//   -> 1 ds_write_b128/thread (T14 split; compiler auto-gates the reg dep).
// B path: global_load_lds with R12's verified swizzle pair (0-conflict).
// Counted pipeline: per-tile vm queue [A(t+2)regs x2, B(t+2)gll x2]; end gate
//   vmcnt(4) = B(t+1) landed; vmcnt(0) only at tail.
// LDS patterns hand-checked conflict-free: A read/write and B read all map
//   8 lanes per 4-bank group (the wave64 b128 floor).
__global__ __launch_bounds__(512, 4)
void diagcn_gemm1(const float* __restrict__ X, const unsigned short* __restrict__ BT,
                  unsigned short* __restrict__ Y) {
  __shared__ unsigned short SH[36864];   // 72 KB: 3 bufs x 12288 elems (A 4096 | B 8192)
  const int tid = threadIdx.x;
  const int w = tid >> 6, lane = tid & 63;
  const int quad = lane >> 4, l15 = lane & 15;
  const int wm = w >> 2, wn = w & 3;     // 2m x 4n wave grid (64x64 per wave)
  const int b = blockIdx.x;
  // XCD-aware bijective swizzle: 1024 blocks = 8 XCDs x 128; n fastest within XCD
  const int wg = ((b & 7) << 7) + (b >> 3);
  const int m0 = (wg >> 2) << 7;         // 256 m-tiles of 128 rows
  const int n0 = (wg & 3) << 8;          // 4 n-tiles of 256 cols
  const int sw8 = ((quad ^ ((l15 >> 1) & 3)) << 3);          // B read-side swizzle
  const int csrc8 = (((lane & 3) ^ ((lane >> 3) & 3)) << 3); // B source-side swizzle
  // A fp32 source: row m0 + (tid>>2), float-chunk (tid&3)*8  (per-thread 8 floats/tile)
  const float* gAx = X + (size_t)(m0 + (tid >> 2)) * 1024 + ((tid & 3) << 3);
  const unsigned short* gB0 = BT + (size_t)(n0 + w * 32 + (lane >> 2)) * 1024 + csrc8;
  // A ds_write dest (elems): row (tid>>2) * 32 + chunk (tid&3) * 8
  const int dA = (tid >> 2) * 32 + ((tid & 3) << 3);

  f32x4 acc[4][4] = {};
  f32x4 s0, s1;

#define G1_COMPUTE(buf)                                                           \
  {                                                                               \
    const unsigned short* Ab = &SH[(buf) * 12288];                                \
    const unsigned short* Bb = &SH[(buf) * 12288 + 4096];                         \
    bf16x8 bv[4];                                                                 \
    _Pragma("unroll")                                                             \
    for (int j = 0; j < 4; ++j)                                                   \
      bv[j] = *(const bf16x8*)&Bb[(wn * 64 + j * 16 + l15) * 32 + sw8];           \
    __builtin_amdgcn_s_setprio(1);                                                \
    _Pragma("unroll")                                                             \
    for (int i = 0; i < 4; ++i) {                                                 \
      bf16x8 av = *(const bf16x8*)&Ab[(wm * 64 + i * 16 + l15) * 32 + quad * 8];  \
      _Pragma("unroll")                                                           \
      for (int j = 0; j < 4; ++j)                                                 \
        acc[i][j] = __builtin_amdgcn_mfma_f32_16x16x32_bf16(av, bv[j], acc[i][j], 0, 0, 0); \
    }                                                                             \
    __builtin_amdgcn_s_setprio(0);                                                \
  }

  // ---- prologue: A0 regs -> buf0; B0 -> buf0; A1 regs; B1 -> buf1
  s0 = *(const f32x4*)(gAx);
  s1 = *(const f32x4*)(gAx + 4);
  {
    unsigned short* bB = &SH[4096 + w * 1024];
    ld_lds16(gB0, bB);
    ld_lds16(gB0 + 16 * 1024, bB + 512);
  }
  *(u16x8*)&SH[dA] = cvt8u(s0, s1);                   // compiler waits A0 loads
  s0 = *(const f32x4*)(gAx + 32);
  s1 = *(const f32x4*)(gAx + 36);
  {
    unsigned short* bB = &SH[12288 + 4096 + w * 1024];
    ld_lds16(gB0 + 32, bB);
    ld_lds16(gB0 + 32 + 16 * 1024, bB + 512);
  }
  asm volatile("s_waitcnt vmcnt(4)" ::: "memory");    // B0 landed (A1,B1 in flight)
  asm volatile("s_waitcnt lgkmcnt(0)");
  __builtin_amdgcn_sched_barrier(0);
  __builtin_amdgcn_s_barrier();

  // ---- main loop: tiles 0..29 (issue t+2; write A(t+1); compute t)
#pragma unroll 1
  for (int t = 0; t < 30; ++t) {
    // ds_write A(t+1) into buf (t+1)%3 (= buf of tile t-2, drained 2 barriers ago)
    *(u16x8*)&SH[((t + 1) % 3) * 12288 + dA] = cvt8u(s0, s1);  // auto vmcnt gate
    // issue tile t+2: A -> regs, B -> buf (t+2)%3 (= buf of tile t-1, drained)
    s0 = *(const f32x4*)(gAx + (t + 2) * 32);
    s1 = *(const f32x4*)(gAx + (t + 2) * 32 + 4);
    {
      unsigned short* bB = &SH[((t + 2) % 3) * 12288 + 4096 + w * 1024];
      ld_lds16(gB0 + (t + 2) * 32, bB);
      ld_lds16(gB0 + (t + 2) * 32 + 16 * 1024, bB + 512);
    }
    G1_COMPUTE(t % 3);
    asm volatile("s_waitcnt vmcnt(4)" ::: "memory");  // B(t+1) landed; t+2 in flight
    asm volatile("s_waitcnt lgkmcnt(0)");             // A(t+1) write + frag reads done
    __builtin_amdgcn_sched_barrier(0);
    __builtin_amdgcn_s_barrier();
  }
  // ---- tail: t=30 (write A31, compute buf0, drain), t=31 (compute buf1)
  *(u16x8*)&SH[(31 % 3) * 12288 + dA] = cvt8u(s0, s1);
  G1_COMPUTE(30 % 3);
  asm volatile("s_waitcnt vmcnt(0)" ::: "memory");    // B31 landed (final drain)
  asm volatile("s_waitcnt lgkmcnt(0)");
  __builtin_amdgcn_sched_barrier(0);
  __builtin_amdgcn_s_barrier();
  G1_COMPUTE(31 % 3);
#undef G1_COMPUTE

  // epilogue: C/D mapping col=lane&15, row=quad*4+r
#pragma unroll
  for (int i = 0; i < 4; ++i)
#pragma unroll
    for (int j = 0; j < 4; ++j) {
      const int row = m0 + wm * 64 + i * 16 + quad * 4;
      const int col = n0 + wn * 64 + j * 16 + l15;
#pragma unroll
      for (int r = 0; r < 4; ++r)
        Y[(size_t)(row + r) * 1024 + col] = f2bf(acc[i][j][r]);
    }
}

// ---- RGCN aggregate, 2 nodes per wave (8 ch/lane, 16B loads), branchless window.
// h_i = Yroot_i + b + sum_r mean_{j in win, rel=r} Y_r[j]; bf16 h -> A2[:,0:256].
__global__ __launch_bounds__(256)
void diagcn_h(const unsigned short* __restrict__ Y, const int* __restrict__ spk,
              const float* __restrict__ brgcn, unsigned short* __restrict__ A2) {
  int b = blockIdx.x;
  int wv = threadIdx.x >> 6, lane = threadIdx.x & 63;
  int half = lane >> 5, li = lane & 31, c0 = li << 3;
  int node = ((b & 7) << 12) + ((b >> 3) << 3) + wv * 2 + half;
  int p = node & 255, dbase = node - p;
  int si = spk[node];
  float a0[8] = {}, a1[8] = {};
  float n0 = 0.f, n1 = 0.f;
#pragma unroll
  for (int d = -4; d <= 4; ++d) {
    int pj = p + d;
    float w = (pj >= 0 && pj < 256) ? 1.f : 0.f;
    int jc = pj < 0 ? 0 : (pj > 255 ? 255 : pj);
    int nj = dbase + jc;
    int rel = si & spk[nj];
    u16x8 v = *(const u16x8*)&Y[(size_t)nj * 1024 + (rel << 8) + c0];
    float w1 = rel ? w : 0.f, w0 = rel ? 0.f : w;
#pragma unroll
    for (int k = 0; k < 8; ++k) {
      float f = bf2f(v[k]);
      a0[k] += f * w0; a1[k] += f * w1;
    }
    n0 += w0; n1 += w1;
  }
  u16x8 vr = *(const u16x8*)&Y[(size_t)node * 1024 + 512 + c0];
  float i0 = 1.f / fmaxf(n0, 1.f), i1 = 1.f / fmaxf(n1, 1.f);
  u16x8 u;
#pragma unroll
  for (int k = 0; k < 8; ++k)
    u[k] = f2bf(bf2f(vr[k]) + brgcn[c0 + k] + a0[k] * i0 + a1[k] * i1);
  *(u16x8*)&A2[(size_t)node * 512 + c0] = u;
}

// ---- GraphConv neighbor sum (aggr=add over window incl. self), 2 nodes/wave.
__global__ __launch_bounds__(256)
void diagcn_neigh(unsigned short* __restrict__ A2) {
  int b = blockIdx.x;
  int wv = threadIdx.x >> 6, lane = threadIdx.x & 63;
  int half = lane >> 5, li = lane & 31, c0 = li << 3;
  int node = ((b & 7) << 12) + ((b >> 3) << 3) + wv * 2 + half;
  int p = node & 255, dbase = node - p;
  float s[8] = {};
#pragma unroll
  for (int d = -4; d <= 4; ++d) {
    int pj = p + d;
    float w = (pj >= 0 && pj < 256) ? 1.f : 0.f;
    int jc = pj < 0 ? 0 : (pj > 255 ? 255 : pj);
    u16x8 v = *(const u16x8*)&A2[(size_t)(dbase + jc) * 512 + c0];
#pragma unroll
    for (int k = 0; k < 8; ++k) s[k] += bf2f(v[k]) * w;
  }
  u16x8 u;
#pragma unroll
  for (int k = 0; k < 8; ++k) u[k] = f2bf(s[k]);
  *(u16x8*)&A2[(size_t)node * 512 + 256 + c0] = u;
}

// ---- GEMM2 v3 + fused epilogue (R10-measured: counted double-buffer pipeline).
__global__ __launch_bounds__(256)
void diagcn_gemm2(const unsigned short* __restrict__ A, const unsigned short* __restrict__ BT,
                  const unsigned short* __restrict__ Y, const float* __restrict__ Wcls,
                  const float* __restrict__ bcls, const float* __restrict__ brel,
                  const float* __restrict__ bskip, const int* __restrict__ labels,
                  float* __restrict__ out, float* __restrict__ loss) {
  const int K = 512;
  __shared__ unsigned short SH[40960];   // 80 KB: 2 bufs x (A 4096 + B 16384 elems)
  const int tid = threadIdx.x;
  const int w = tid >> 6, lane = tid & 63;
  const int quad = lane >> 4, l15 = lane & 15;
  const int b = blockIdx.x;
  const int m0 = (((b & 7) << 6) + (b >> 3)) << 6;   // 512 m-tiles of 64 rows
  const int rowg = lane >> 3;
  const int kbsw = (lane & 7) ^ rowg;

  f32x4 acc[16] = {};
  const unsigned short* Abase = A + (size_t)m0 * K + kbsw * 8;
  const unsigned short* Bbase = BT + kbsw * 8;
  const unsigned short* Ybase = Y + (size_t)(m0 + (lane >> 5)) * 1024 + 768 + (lane & 31) * 8;

#define G2_STAGE(t, buf)                                                        \
  {                                                                             \
    unsigned short* As_ = SH + (buf) * 20480;                                   \
    unsigned short* Bs_ = As_ + 4096;                                           \
    int k0_ = (t) * 64;                                                         \
    _Pragma("unroll")                                                           \
    for (int i = 0; i < 2; ++i) {                                               \
      int grp = w * 2 + i;                                                      \
      ld_lds16(Abase + (size_t)(grp * 8 + rowg) * K + k0_, &As_[grp * 512]);    \
    }                                                                           \
    _Pragma("unroll")                                                           \
    for (int i = 0; i < 8; ++i) {                                               \
      int grp = w * 8 + i;                                                      \
      ld_lds16(Bbase + (size_t)(grp * 8 + rowg) * K + k0_, &Bs_[grp * 512]);    \
    }                                                                           \
  }
#define G2_COMPUTE(buf)                                                         \
  {                                                                             \
    const unsigned short* As_ = SH + (buf) * 20480;                             \
    const unsigned short* Bs_ = As_ + 4096;                                     \
    _Pragma("unroll")                                                           \
    for (int ks = 0; ks < 2; ++ks) {                                            \
      int kb = ks * 4 + quad;                                                   \
      int ra = w * 16 + l15;                                                    \
      bf16x8 av = *(const bf16x8*)&As_[ra * 64 + ((kb ^ (ra & 7)) << 3)];       \
      _Pragma("unroll")                                                         \
      for (int j = 0; j < 16; ++j) {                                            \
        int rb2 = j * 16 + l15;                                                 \
        bf16x8 bv = *(const bf16x8*)&Bs_[rb2 * 64 + ((kb ^ (rb2 & 7)) << 3)];   \
        acc[j] = __builtin_amdgcn_mfma_f32_16x16x32_bf16(av, bv, acc[j], 0, 0, 0); \
      }                                                                         \
    }                                                                           \
  }

  G2_STAGE(0, 0);
  G2_STAGE(1, 1);
  asm volatile("s_waitcnt vmcnt(10)" ::: "memory");   // tile 0 landed
  __builtin_amdgcn_s_barrier();

#pragma unroll 1
  for (int t = 0; t < 6; ++t) {
    G2_COMPUTE(t & 1);
    asm volatile("s_waitcnt lgkmcnt(0)" ::: "memory");
    __builtin_amdgcn_s_barrier();
    G2_STAGE(t + 2, t & 1);
    asm volatile("s_waitcnt vmcnt(10)" ::: "memory");
    __builtin_amdgcn_s_barrier();
  }
  G2_COMPUTE(0);                                       // tile 6
  asm volatile("s_waitcnt lgkmcnt(0)" ::: "memory");
  __builtin_amdgcn_s_barrier();
  asm volatile("s_waitcnt vmcnt(0)" ::: "memory");     // tile 7 landed
  __builtin_amdgcn_s_barrier();
#pragma unroll
  for (int i = 0; i < 8; ++i) {
    int g = w * 8 + i;
    ld_lds16(Ybase + (size_t)g * 2048, &SH[g * 512]);  // Y-skip tile into freed buf0
  }
  G2_COMPUTE(1);                                       // tile 7
  asm volatile("s_waitcnt vmcnt(0)" ::: "memory");     // Y landed
  __builtin_amdgcn_s_barrier();

  float wsum[4][7] = {};
#pragma unroll
  for (int j = 0; j < 16; ++j) {
    int col = j * 16 + l15;
    float bb = brel[col] + bskip[col];
#pragma unroll
    for (int r = 0; r < 4; ++r) {
      int rl = w * 16 + quad * 4 + r;
      float z = acc[j][r] + bb + bf2f(SH[rl * 256 + col]);
#pragma unroll
      for (int c = 0; c < 7; ++c) wsum[r][c] += z * Wcls[col * 7 + c];
    }
  }
#pragma unroll
  for (int o = 1; o < 16; o <<= 1)
#pragma unroll
    for (int r = 0; r < 4; ++r)
#pragma unroll
      for (int c = 0; c < 7; ++c) wsum[r][c] += __shfl_xor(wsum[r][c], o, 64);

  float lsum = 0.f;
#pragma unroll
  for (int r = 0; r < 4; ++r) {
    int row = m0 + w * 16 + quad * 4 + r;
    float o7[7], mx = -1e30f;
#pragma unroll
    for (int c = 0; c < 7; ++c) {
      o7[c] = wsum[r][c] + bcls[c];
      mx = fmaxf(mx, o7[c]);
    }
    if (l15 < 7) out[(size_t)row * 7 + l15] = o7[l15];
    float s = 0.f;
#pragma unroll
    for (int c = 0; c < 7; ++c) s += expf(o7[c] - mx);
    int lab = labels[row];
    lsum += mx + logf(s) - o7[lab];
  }
  lsum += __shfl_xor(lsum, 16, 64);
  lsum += __shfl_xor(lsum, 32, 64);
  if (lane == 0) atomicAdd(loss, lsum * (1.0f / (float)NN));
#undef G2_STAGE
#undef G2_COMPUTE
}

extern "C" void kernel_launch(void* const* d_in, const int* in_sizes, int n_in,
                              void* d_out, int out_size, void* d_ws, size_t ws_size,
                              hipStream_t stream) {
  const float* x      = (const float*)d_in[0];
  const int* speakers = (const int*)d_in[2];
  const int* labels   = (const int*)d_in[3];
  const float* Wrgcn  = (const float*)d_in[6];
  const float* Wroot  = (const float*)d_in[7];
  const float* brgcn  = (const float*)d_in[8];
  const float* Wrel   = (const float*)d_in[9];
  const float* brel   = (const float*)d_in[10];
  const float* Wgrt   = (const float*)d_in[11];
  const float* Wskip  = (const float*)d_in[12];
  const float* bskip  = (const float*)d_in[13];
  const float* Wcls   = (const float*)d_in[14];
  const float* bcls   = (const float*)d_in[15];
  float* out = (float*)d_out;
  float* loss = out + (size_t)NN * 7;

  // workspace layout (bytes) — Xbf eliminated (X read as fp32 by gemm1)
  const size_t OFF_WBIG = 0;                  //  2,097,152
  const size_t OFF_WSM  = 2097152;            //    262,144
  const size_t OFF_Y    = 2359296;            // 67,108,864  (bf16 [Y0|Y1|Yroot|Yskip])
  const size_t OFF_A2   = 69468160;           // 33,554,432  (bf16 [h|neigh])
  const size_t NEED     = 103022592;
  if (ws_size < NEED) return;

  char* ws = (char*)d_ws;
  unsigned short* WbigT = (unsigned short*)(ws + OFF_WBIG);
  unsigned short* WsmT  = (unsigned short*)(ws + OFF_WSM);
  unsigned short* Y     = (unsigned short*)(ws + OFF_Y);
  unsigned short* A2    = (unsigned short*)(ws + OFF_A2);

  diagcn_prep<<<dim3(288), dim3(256), 0, stream>>>(Wrgcn, Wroot, Wskip, Wgrt, Wrel,
                                                   WbigT, WsmT, loss);
  diagcn_gemm1<<<dim3(1024), dim3(512), 0, stream>>>(x, WbigT, Y);
  diagcn_h<<<dim3(NN / 8), dim3(256), 0, stream>>>(Y, speakers, brgcn, A2);
  diagcn_neigh<<<dim3(NN / 8), dim3(256), 0, stream>>>(A2);
  diagcn_gemm2<<<dim3(512), dim3(256), 0, stream>>>(A2, WsmT, Y, Wcls, bcls, brel, bskip,
                                                    labels, out, loss);
}